// Round 2
// baseline (2548.449 us; speedup 1.0000x reference)
//
#include <hip/hip_runtime.h>
#include <math.h>

#define NE 32
#define HID 2880
#define TT 64            // tokens per block
#define THREADS 1024     // 16 waves
#define NW 16
#define CK 192           // k-chunk width staged in LDS
#define NCHUNK 15        // 2880 / 192
#define WS 12            // k per wave per chunk (CK/NW)
#define RS 192           // LDS row stride in floats (no pad needed; XOR swizzle)

__global__ void __launch_bounds__(THREADS, 4) router_gemm(
    const float* __restrict__ hs,     // [T][HID]
    const float* __restrict__ w,      // [NE][HID]
    const float* __restrict__ bias,   // [NE]
    float* __restrict__ out,          // [T][NE] scores, then [T][4] idx-as-float
    int T)
{
  __shared__ float hbuf[TT * RS];     // 49152 B
  __shared__ float part[4][TT][36];   // 36864 B  (stride 36: 16B-aligned, bank-uniform)

  const int tid  = threadIdx.x;
  const int wv   = tid >> 6;
  const int lane = tid & 63;
  const int t0   = blockIdx.x * TT;

  // ---- staging: 3 float4 per thread per chunk; row = f/48, c4 = f%48 ----
  float4 sreg0, sreg1, sreg2;
  int srow[3], scol[3];
#pragma unroll
  for (int i = 0; i < 3; ++i) {
    int f = tid + THREADS * i;
    srow[i] = f / 48;
    scol[i] = f % 48;
  }

#define STAGE_LOAD(c)                                                          \
  {                                                                            \
    const float* b0 = hs + (size_t)(t0 + srow[0]) * HID + (c) * CK;            \
    const float* b1 = hs + (size_t)(t0 + srow[1]) * HID + (c) * CK;            \
    const float* b2 = hs + (size_t)(t0 + srow[2]) * HID + (c) * CK;            \
    sreg0 = *(const float4*)(b0 + scol[0] * 4);                                \
    sreg1 = *(const float4*)(b1 + scol[1] * 4);                                \
    sreg2 = *(const float4*)(b2 + scol[2] * 4);                                \
  }

#define STAGE_WRITE()                                                          \
  {                                                                            \
    *(float4*)(hbuf + srow[0] * RS + 4 * (scol[0] ^ (srow[0] & 7))) = sreg0;   \
    *(float4*)(hbuf + srow[1] * RS + 4 * (scol[1] ^ (srow[1] & 7))) = sreg1;   \
    *(float4*)(hbuf + srow[2] * RS + 4 * (scol[2] ^ (srow[2] & 7))) = sreg2;   \
  }

  float acc[NE];
#pragma unroll
  for (int e = 0; e < NE; ++e) acc[e] = 0.f;

  // prologue
  STAGE_LOAD(0);
  STAGE_WRITE();
  STAGE_LOAD(1);
  __syncthreads();

  for (int c = 0; c < NCHUNK; ++c) {
    // ---- compute chunk c: wave wv owns k-slice [c*CK + wv*WS, +WS) ----
    float hreg[WS];
#pragma unroll
    for (int j4 = 0; j4 < 3; ++j4) {
      int c4 = wv * 3 + j4;
      float4 hv = *(const float4*)(hbuf + lane * RS + 4 * (c4 ^ (lane & 7)));
      hreg[j4 * 4 + 0] = hv.x;
      hreg[j4 * 4 + 1] = hv.y;
      hreg[j4 * 4 + 2] = hv.z;
      hreg[j4 * 4 + 3] = hv.w;
    }
    const float* wp = w + c * CK + wv * WS;
#pragma unroll
    for (int e = 0; e < NE; ++e) {
      const float* we = wp + (size_t)e * HID;
      float4 w0 = *(const float4*)(we);
      float4 w1 = *(const float4*)(we + 4);
      float4 w2 = *(const float4*)(we + 8);
      acc[e] = fmaf(hreg[0],  w0.x, acc[e]);
      acc[e] = fmaf(hreg[1],  w0.y, acc[e]);
      acc[e] = fmaf(hreg[2],  w0.z, acc[e]);
      acc[e] = fmaf(hreg[3],  w0.w, acc[e]);
      acc[e] = fmaf(hreg[4],  w1.x, acc[e]);
      acc[e] = fmaf(hreg[5],  w1.y, acc[e]);
      acc[e] = fmaf(hreg[6],  w1.z, acc[e]);
      acc[e] = fmaf(hreg[7],  w1.w, acc[e]);
      acc[e] = fmaf(hreg[8],  w2.x, acc[e]);
      acc[e] = fmaf(hreg[9],  w2.y, acc[e]);
      acc[e] = fmaf(hreg[10], w2.z, acc[e]);
      acc[e] = fmaf(hreg[11], w2.w, acc[e]);
    }
    __syncthreads();   // all waves done reading hbuf
    if (c + 1 < NCHUNK) {
      STAGE_WRITE();   // write chunk c+1 (regs loaded 2 iterations ahead)
      if (c + 2 < NCHUNK) STAGE_LOAD(c + 2);
    }
    __syncthreads();   // chunk c+1 visible
  }

  // ---- reduce 16 waves -> part[4] in 4 phases ----
  const int q = wv & 3, p = wv >> 2;
#pragma unroll
  for (int ph = 0; ph < 4; ++ph) {
    if (p == ph) {
      if (ph == 0) {
#pragma unroll
        for (int e = 0; e < NE; e += 4) {
          float4 v;
          v.x = acc[e]; v.y = acc[e + 1]; v.z = acc[e + 2]; v.w = acc[e + 3];
          *(float4*)(&part[q][lane][e]) = v;
        }
      } else {
#pragma unroll
        for (int e = 0; e < NE; e += 4) {
          float4 v = *(float4*)(&part[q][lane][e]);
          v.x += acc[e]; v.y += acc[e + 1]; v.z += acc[e + 2]; v.w += acc[e + 3];
          *(float4*)(&part[q][lane][e]) = v;
        }
      }
    }
    __syncthreads();
  }

  // ---- wave 0: logits = sum(part) + bias; top-4; softmax; scatter ----
  if (wv == 0) {
    float lg[NE];
#pragma unroll
    for (int e = 0; e < NE; e += 4) {
      float4 a = *(float4*)(&part[0][lane][e]);
      float4 b = *(float4*)(&part[1][lane][e]);
      float4 cc = *(float4*)(&part[2][lane][e]);
      float4 d = *(float4*)(&part[3][lane][e]);
      float4 bb = *(const float4*)(bias + e);
      lg[e]     = a.x + b.x + cc.x + d.x + bb.x;
      lg[e + 1] = a.y + b.y + cc.y + d.y + bb.y;
      lg[e + 2] = a.z + b.z + cc.z + d.z + bb.z;
      lg[e + 3] = a.w + b.w + cc.w + d.w + bb.w;
    }

    float tv[4]; int ti[4];
#pragma unroll
    for (int kk = 0; kk < 4; ++kk) {
      float m = -INFINITY; int mi = 0;
#pragma unroll
      for (int e = 0; e < NE; ++e) {
        bool gt = lg[e] > m;      // strict >: lowest index wins ties (jax semantics)
        m  = gt ? lg[e] : m;
        mi = gt ? e : mi;
      }
      tv[kk] = m; ti[kk] = mi;
#pragma unroll
      for (int e = 0; e < NE; ++e)
        lg[e] = (e == mi) ? -INFINITY : lg[e];
    }

    float e1 = __expf(tv[1] - tv[0]);
    float e2 = __expf(tv[2] - tv[0]);
    float e3 = __expf(tv[3] - tv[0]);
    float inv = 1.0f / (1.0f + e1 + e2 + e3);
    float pr[4] = {inv, e1 * inv, e2 * inv, e3 * inv};

    const int tok = t0 + lane;
    float* orow = out + (size_t)tok * NE;
#pragma unroll
    for (int g = 0; g < 8; ++g) {
      float4 v;
      float* vp = (float*)&v;
#pragma unroll
      for (int cb = 0; cb < 4; ++cb) {
        int e = g * 4 + cb;
        float x = 0.f;
        x = (e == ti[0]) ? pr[0] : x;
        x = (e == ti[1]) ? pr[1] : x;
        x = (e == ti[2]) ? pr[2] : x;
        x = (e == ti[3]) ? pr[3] : x;
        vp[cb] = x;
      }
      *(float4*)(orow + g * 4) = v;
    }
    float* oidx = out + (size_t)T * NE + (size_t)tok * 4;
    float4 iv;
    iv.x = (float)ti[0]; iv.y = (float)ti[1]; iv.z = (float)ti[2]; iv.w = (float)ti[3];
    *(float4*)oidx = iv;
  }
}

extern "C" void kernel_launch(void* const* d_in, const int* in_sizes, int n_in,
                              void* d_out, int out_size, void* d_ws, size_t ws_size,
                              hipStream_t stream) {
  const float* hs   = (const float*)d_in[0];
  const float* w    = (const float*)d_in[1];
  const float* bias = (const float*)d_in[2];
  float* out        = (float*)d_out;

  const int T = in_sizes[0] / HID;   // 16384
  const int blocks = T / TT;         // 256

  hipLaunchKernelGGL(router_gemm, dim3(blocks), dim3(THREADS), 0, stream,
                     hs, w, bias, out, T);
}

// Round 3
// 198.621 us; speedup vs baseline: 12.8307x; 12.8307x over previous
//
#include <hip/hip_runtime.h>
#include <math.h>

#define NE 32
#define HID 2880
#define TT 64            // tokens per block
#define THREADS 1024     // 16 waves
#define NW 16
#define CK 192           // k-chunk width staged in LDS
#define NCHUNK 15        // 2880 / 192
#define WS 12            // k per wave per chunk (CK/NW)
#define RS 192           // LDS row stride in floats (XOR swizzle, no pad)

__global__ void __launch_bounds__(THREADS) router_gemm(
    const float* __restrict__ hs,     // [T][HID]
    const float* __restrict__ w,      // [NE][HID]
    const float* __restrict__ bias,   // [NE]
    float* __restrict__ out,          // [T][NE] scores, then [T][4] idx-as-float
    int T)
{
  __shared__ float hbuf[TT * RS];     // 49152 B
  __shared__ float part[4][TT][36];   // 36864 B (stride 36: 16B-aligned, conflict-free)

  const int tid  = threadIdx.x;
  const int wv   = __builtin_amdgcn_readfirstlane(tid >> 6);  // SGPR wave id
  const int lane = tid & 63;
  const int t0   = blockIdx.x * TT;

  // ---- staging: 3 float4 per thread per chunk; row = f/48, c4 = f%48 ----
  float4 sreg0, sreg1, sreg2;
  int srow[3], scol[3];
#pragma unroll
  for (int i = 0; i < 3; ++i) {
    int f = tid + THREADS * i;
    srow[i] = f / 48;
    scol[i] = f % 48;
  }

#define STAGE_LOAD(c)                                                          \
  {                                                                            \
    const float* b0 = hs + (size_t)(t0 + srow[0]) * HID + (c) * CK;            \
    const float* b1 = hs + (size_t)(t0 + srow[1]) * HID + (c) * CK;            \
    const float* b2 = hs + (size_t)(t0 + srow[2]) * HID + (c) * CK;            \
    sreg0 = *(const float4*)(b0 + scol[0] * 4);                                \
    sreg1 = *(const float4*)(b1 + scol[1] * 4);                                \
    sreg2 = *(const float4*)(b2 + scol[2] * 4);                                \
  }

#define STAGE_WRITE()                                                          \
  {                                                                            \
    *(float4*)(hbuf + srow[0] * RS + 4 * (scol[0] ^ (srow[0] & 7))) = sreg0;   \
    *(float4*)(hbuf + srow[1] * RS + 4 * (scol[1] ^ (srow[1] & 7))) = sreg1;   \
    *(float4*)(hbuf + srow[2] * RS + 4 * (scol[2] ^ (srow[2] & 7))) = sreg2;   \
  }

  float acc[NE];
#pragma unroll
  for (int e = 0; e < NE; ++e) acc[e] = 0.f;

  // prologue
  STAGE_LOAD(0);
  STAGE_WRITE();
  STAGE_LOAD(1);
  __syncthreads();

  for (int c = 0; c < NCHUNK; ++c) {
    // ---- compute chunk c: wave wv owns k-slice [c*CK + wv*WS, +WS) ----
    float hreg[WS];
#pragma unroll
    for (int j4 = 0; j4 < 3; ++j4) {
      int c4 = wv * 3 + j4;
      float4 hv = *(const float4*)(hbuf + lane * RS + 4 * (c4 ^ (lane & 7)));
      hreg[j4 * 4 + 0] = hv.x;
      hreg[j4 * 4 + 1] = hv.y;
      hreg[j4 * 4 + 2] = hv.z;
      hreg[j4 * 4 + 3] = hv.w;
    }
    // W pointer is wave-uniform (wv in SGPR) -> s_load path, W stays in SGPRs
    const float* wp = w + c * CK + wv * WS;
#pragma unroll
    for (int eg = 0; eg < 4; ++eg) {       // 4 groups of 8 experts
#pragma unroll
      for (int ei = 0; ei < 8; ++ei) {
        const int e = eg * 8 + ei;
        const float* we = wp + (size_t)e * HID;
        float4 w0 = *(const float4*)(we);
        float4 w1 = *(const float4*)(we + 4);
        float4 w2 = *(const float4*)(we + 8);
        acc[e] = fmaf(hreg[0],  w0.x, acc[e]);
        acc[e] = fmaf(hreg[1],  w0.y, acc[e]);
        acc[e] = fmaf(hreg[2],  w0.z, acc[e]);
        acc[e] = fmaf(hreg[3],  w0.w, acc[e]);
        acc[e] = fmaf(hreg[4],  w1.x, acc[e]);
        acc[e] = fmaf(hreg[5],  w1.y, acc[e]);
        acc[e] = fmaf(hreg[6],  w1.z, acc[e]);
        acc[e] = fmaf(hreg[7],  w1.w, acc[e]);
        acc[e] = fmaf(hreg[8],  w2.x, acc[e]);
        acc[e] = fmaf(hreg[9],  w2.y, acc[e]);
        acc[e] = fmaf(hreg[10], w2.z, acc[e]);
        acc[e] = fmaf(hreg[11], w2.w, acc[e]);
      }
    }
    __syncthreads();   // all waves done reading hbuf
    if (c + 1 < NCHUNK) {
      STAGE_WRITE();   // write chunk c+1 (regs loaded 2 iterations ahead)
      if (c + 2 < NCHUNK) STAGE_LOAD(c + 2);
    }
    __syncthreads();   // chunk c+1 visible
  }

  // ---- reduce 16 waves -> part[4] in 4 phases ----
  const int q = wv & 3, p = wv >> 2;
#pragma unroll
  for (int ph = 0; ph < 4; ++ph) {
    if (p == ph) {
      if (ph == 0) {
#pragma unroll
        for (int e = 0; e < NE; e += 4) {
          float4 v;
          v.x = acc[e]; v.y = acc[e + 1]; v.z = acc[e + 2]; v.w = acc[e + 3];
          *(float4*)(&part[q][lane][e]) = v;
        }
      } else {
#pragma unroll
        for (int e = 0; e < NE; e += 4) {
          float4 v = *(float4*)(&part[q][lane][e]);
          v.x += acc[e]; v.y += acc[e + 1]; v.z += acc[e + 2]; v.w += acc[e + 3];
          *(float4*)(&part[q][lane][e]) = v;
        }
      }
    }
    __syncthreads();
  }

  // ---- wave 0: logits = sum(part) + bias; top-4; softmax; scatter ----
  if (wv == 0) {
    float lg[NE];
#pragma unroll
    for (int e = 0; e < NE; e += 4) {
      float4 a  = *(float4*)(&part[0][lane][e]);
      float4 b  = *(float4*)(&part[1][lane][e]);
      float4 cc = *(float4*)(&part[2][lane][e]);
      float4 d  = *(float4*)(&part[3][lane][e]);
      float4 bb = *(const float4*)(bias + e);
      lg[e]     = a.x + b.x + cc.x + d.x + bb.x;
      lg[e + 1] = a.y + b.y + cc.y + d.y + bb.y;
      lg[e + 2] = a.z + b.z + cc.z + d.z + bb.z;
      lg[e + 3] = a.w + b.w + cc.w + d.w + bb.w;
    }

    float tv[4]; int ti[4];
#pragma unroll
    for (int kk = 0; kk < 4; ++kk) {
      float m = -INFINITY; int mi = 0;
#pragma unroll
      for (int e = 0; e < NE; ++e) {
        bool gt = lg[e] > m;      // strict >: lowest index wins ties (jax semantics)
        m  = gt ? lg[e] : m;
        mi = gt ? e : mi;
      }
      tv[kk] = m; ti[kk] = mi;
#pragma unroll
      for (int e = 0; e < NE; ++e)
        lg[e] = (e == mi) ? -INFINITY : lg[e];
    }

    float e1 = __expf(tv[1] - tv[0]);
    float e2 = __expf(tv[2] - tv[0]);
    float e3 = __expf(tv[3] - tv[0]);
    float inv = 1.0f / (1.0f + e1 + e2 + e3);
    float pr[4] = {inv, e1 * inv, e2 * inv, e3 * inv};

    const int tok = t0 + lane;
    float* orow = out + (size_t)tok * NE;
#pragma unroll
    for (int g = 0; g < 8; ++g) {
      float4 v;
      float* vp = (float*)&v;
#pragma unroll
      for (int cb = 0; cb < 4; ++cb) {
        int e = g * 4 + cb;
        float x = 0.f;
        x = (e == ti[0]) ? pr[0] : x;
        x = (e == ti[1]) ? pr[1] : x;
        x = (e == ti[2]) ? pr[2] : x;
        x = (e == ti[3]) ? pr[3] : x;
        vp[cb] = x;
      }
      *(float4*)(orow + g * 4) = v;
    }
    float* oidx = out + (size_t)T * NE + (size_t)tok * 4;
    float4 iv;
    iv.x = (float)ti[0]; iv.y = (float)ti[1]; iv.z = (float)ti[2]; iv.w = (float)ti[3];
    *(float4*)oidx = iv;
  }
}

extern "C" void kernel_launch(void* const* d_in, const int* in_sizes, int n_in,
                              void* d_out, int out_size, void* d_ws, size_t ws_size,
                              hipStream_t stream) {
  const float* hs   = (const float*)d_in[0];
  const float* w    = (const float*)d_in[1];
  const float* bias = (const float*)d_in[2];
  float* out        = (float*)d_out;

  const int T = in_sizes[0] / HID;   // 16384
  const int blocks = T / TT;         // 256

  hipLaunchKernelGGL(router_gemm, dim3(blocks), dim3(THREADS), 0, stream,
                     hs, w, bias, out, T);
}